// Round 3
// baseline (686.054 us; speedup 1.0000x reference)
//
#include <hip/hip_runtime.h>
#include <cstdint>
#include <cstddef>

#define K_DIM 4096
#define N_DIM 4096
#define BM 256
#define BN 256
#define BK 64            // K-step; LDS row = 128 B = full bank period
#define NT (K_DIM / BK)  // 64 K-tiles

typedef __attribute__((ext_vector_type(8))) short short8;
typedef __attribute__((ext_vector_type(4))) float floatx4;

// fp32x2 -> packed bf16x2 (RNE) — single HW instruction on gfx950.
__device__ __forceinline__ unsigned cvt_pk_bf16(float lo, float hi) {
    unsigned r;
    asm("v_cvt_pk_bf16_f32 %0, %1, %2" : "=v"(r) : "v"(lo), "v"(hi));
    return r;
}

// ---------------------------------------------------------------------------
// Fused-cast bf16 GEMM, C = A * B^T, reading fp32 A (x) and fp32 B (w)
// directly. 256x256 tile / 512 threads (8 waves 2Mx4N), 4-phase-per-K-tile
// ring schedule. No separate cast kernel: staging is
// global float4 -> v_cvt_pk_bf16_f32 -> swizzled ds_write_b64 (reg-staging,
// HK pattern), T14-split: loads at phase top, cvt+writes after the MFMA.
//
// LDS: ring of 4 half-tiles per matrix (128 rows x 64 halves = 16 KiB each),
//   A(k,h) -> slot (2k+h)&3; same for B. Total 128 KiB.
// Swizzle: physical 16B-block = logical_kblk ^ (row & 7), applied on the
//   ds_write side (write: (l16>>1)^(base_r&7); read: ((ks<<2)|quad)^(l16&7) —
//   same involution both sides; read side identical to the measured
//   0-bank-conflict kernel).
//
// Hazards (hand-verified):
//   write(slot) at phase N -> first cross-wave read at N+4. DS ops complete
//   in order per wave; the writer's own phase-N+1 ds_read lgkm-wait retires
//   the phase-N writes, and the N+1 barrier orders them cross-wave. Safe.
//   read(slot) -> re-write(slot): >= 2 barriers. Safe.
// Compiler fence (asm "" memory) before each s_barrier: s_barrier is
// IntrNoMem at IR level, so without the fence IR passes could in principle
// move plain LDS ops across it.
// ---------------------------------------------------------------------------
typedef struct { float4 t0, t1, t2, t3; } StageRegs;

__global__ __launch_bounds__(512, 2) void gemm_bf16_bt(
        const float* __restrict__ X,
        const float* __restrict__ W,
        float* __restrict__ C, int M) {
    __shared__ unsigned short sAb[4 * 128 * 64];   // 64 KiB: 4 half-tile slots
    __shared__ unsigned short sBb[4 * 128 * 64];   // 64 KiB

    const int tid  = threadIdx.x;
    const int lane = tid & 63;
    const int wave = tid >> 6;        // 0..7
    const int wqm  = wave >> 2;       // 0..1: M-half of wave within a C-quadrant
    const int wqn  = wave & 3;        // 0..3: N-quarter of wave within a C-quadrant
    const int quad = lane >> 4;       // 0..3
    const int l16  = lane & 15;

    // XCD-aware swizzle (bijective: nwg % 8 == 0 by construction)
    const int nbn = N_DIM / BN;       // 16
    int wg = blockIdx.x;
    const int cpx = gridDim.x >> 3;
    wg = (wg & 7) * cpx + (wg >> 3);
    const int bm = wg / nbn;
    const int bn = wg % nbn;

    // staging addresses: thread covers rows base_r + 32*i (i=0..3),
    // floats [l16*4, l16*4+4) of each 64-float row chunk.
    const int base_r = wave * 4 + (lane >> 4);              // 0..31
    const float* ax = X + ((size_t)bm * BM + base_r) * K_DIM + (size_t)l16 * 4;
    const float* bx = W + ((size_t)bn * BN + base_r) * K_DIM + (size_t)l16 * 4;
    // LDS write base (in shorts), swizzled: block (l16>>1) ^ (base_r&7)
    const int wbase = base_r * 64 + (((l16 >> 1) ^ (base_r & 7)) << 3)
                    + ((l16 & 1) << 2);

#define STAGE_LOAD(R, gsrc, half, kt)                                            \
    do {                                                                         \
        const float* g_ = (gsrc) + ((size_t)(half) * 128) * K_DIM                \
                                 + (size_t)(kt) * BK;                            \
        (R).t0 = *(const float4*)(g_);                                           \
        (R).t1 = *(const float4*)(g_ + (size_t)32 * K_DIM);                      \
        (R).t2 = *(const float4*)(g_ + (size_t)64 * K_DIM);                      \
        (R).t3 = *(const float4*)(g_ + (size_t)96 * K_DIM);                      \
    } while (0)

#define STAGE_WRITE(R, sptr, slot)                                               \
    do {                                                                         \
        unsigned short* w_ = (sptr) + (slot) * 8192 + wbase;                     \
        *(uint2*)(w_ +    0) = make_uint2(cvt_pk_bf16((R).t0.x, (R).t0.y),       \
                                          cvt_pk_bf16((R).t0.z, (R).t0.w));      \
        *(uint2*)(w_ + 2048) = make_uint2(cvt_pk_bf16((R).t1.x, (R).t1.y),       \
                                          cvt_pk_bf16((R).t1.z, (R).t1.w));      \
        *(uint2*)(w_ + 4096) = make_uint2(cvt_pk_bf16((R).t2.x, (R).t2.y),       \
                                          cvt_pk_bf16((R).t2.z, (R).t2.w));      \
        *(uint2*)(w_ + 6144) = make_uint2(cvt_pk_bf16((R).t3.x, (R).t3.y),       \
                                          cvt_pk_bf16((R).t3.z, (R).t3.w));      \
    } while (0)

    floatx4 acc[2][2][4][2];
#pragma unroll
    for (int a = 0; a < 2; ++a)
#pragma unroll
        for (int b = 0; b < 2; ++b)
#pragma unroll
            for (int c = 0; c < 4; ++c)
#pragma unroll
                for (int d = 0; d < 2; ++d)
                    acc[a][b][c][d] = (floatx4)0.0f;

    short8 af[4][2];        // A frags for current qm (reused across 2 phases)
    short8 bf0[2][2];       // B frags qn=0 (live whole tile)
    short8 bf1[2][2];       // B frags qn=1

    // frag reads (swizzled, conflict-free: row&7 == l16&7 everywhere)
#define LDA(slot)                                                                \
    do {                                                                         \
        _Pragma("unroll")                                                        \
        for (int mt_ = 0; mt_ < 4; ++mt_)                                        \
        _Pragma("unroll")                                                        \
        for (int ks_ = 0; ks_ < 2; ++ks_)                                        \
            af[mt_][ks_] = *(const short8*)(sAb + (slot) * 8192 +                \
                (wqm * 64 + mt_ * 16 + l16) * BK +                               \
                ((((ks_ << 2) | quad) ^ (l16 & 7)) << 3));                       \
    } while (0)

#define LDB(dst, slot)                                                           \
    do {                                                                         \
        _Pragma("unroll")                                                        \
        for (int nt_ = 0; nt_ < 2; ++nt_)                                        \
        _Pragma("unroll")                                                        \
        for (int ks_ = 0; ks_ < 2; ++ks_)                                        \
            dst[nt_][ks_] = *(const short8*)(sBb + (slot) * 8192 +               \
                (wqn * 32 + nt_ * 16 + l16) * BK +                               \
                ((((ks_ << 2) | quad) ^ (l16 & 7)) << 3));                       \
    } while (0)

#define MMA(qm, qn, bfv)                                                         \
    do {                                                                         \
        __builtin_amdgcn_s_setprio(1);                                           \
        _Pragma("unroll")                                                        \
        for (int mt_ = 0; mt_ < 4; ++mt_)                                        \
        _Pragma("unroll")                                                        \
        for (int nt_ = 0; nt_ < 2; ++nt_)                                        \
        _Pragma("unroll")                                                        \
        for (int ks_ = 0; ks_ < 2; ++ks_)                                        \
            acc[qm][qn][mt_][nt_] = __builtin_amdgcn_mfma_f32_16x16x32_bf16(     \
                af[mt_][ks_], bfv[nt_][ks_], acc[qm][qn][mt_][nt_], 0, 0, 0);    \
        __builtin_amdgcn_s_setprio(0);                                           \
    } while (0)

#define ENDPHASE()                                                               \
    do {                                                                         \
        asm volatile("" ::: "memory");   /* IR-level fence: nothing crosses */   \
        __builtin_amdgcn_s_barrier();                                            \
        __builtin_amdgcn_sched_barrier(0);                                       \
    } while (0)

    // P0 = (k&1)*2 (compile-time via 2x loop unroll)
#define TILE(P0, k)                                                              \
    do {                                                                         \
        { StageRegs r_;                                                          \
          STAGE_LOAD(r_, ax, 1, (k) + 1);       /* A(k+1,1) */                   \
          LDA((P0));                                                             \
          LDB(bf0, (P0));                                                        \
          MMA(0, 0, bf0);                                                        \
          STAGE_WRITE(r_, sAb, ((P0) ^ 2) + 1);                                  \
        } ENDPHASE();                                                            \
        { StageRegs r_;                                                          \
          STAGE_LOAD(r_, bx, 1, (k) + 1);       /* B(k+1,1) */                   \
          LDB(bf1, (P0) + 1);                                                    \
          MMA(0, 1, bf1);                                                        \
          STAGE_WRITE(r_, sBb, ((P0) ^ 2) + 1);                                  \
        } ENDPHASE();                                                            \
        { StageRegs r_;                                                          \
          STAGE_LOAD(r_, ax, 0, (k) + 2);       /* A(k+2,0) */                   \
          LDA((P0) + 1);                                                         \
          MMA(1, 0, bf0);                                                        \
          STAGE_WRITE(r_, sAb, (P0));                                            \
        } ENDPHASE();                                                            \
        { StageRegs r_;                                                          \
          STAGE_LOAD(r_, bx, 0, (k) + 2);       /* B(k+2,0) */                   \
          MMA(1, 1, bf1);                                                        \
          STAGE_WRITE(r_, sBb, (P0));                                            \
        } ENDPHASE();                                                            \
    } while (0)

#define TILE_NOSYNC(P0)                                                          \
    do {                                                                         \
        LDA((P0));     LDB(bf0, (P0)); MMA(0, 0, bf0);                           \
        LDB(bf1, (P0) + 1);            MMA(0, 1, bf1);                           \
        LDA((P0) + 1);                 MMA(1, 0, bf0);                           \
                                       MMA(1, 1, bf1);                           \
    } while (0)

    // ---- prologue: stage A/B (0,0)->0, (0,1)->1, (1,0)->2 ----
    {
        StageRegs rA, rB;
        STAGE_LOAD(rA, ax, 0, 0); STAGE_LOAD(rB, bx, 0, 0);
        STAGE_WRITE(rA, sAb, 0);  STAGE_WRITE(rB, sBb, 0);
        STAGE_LOAD(rA, ax, 1, 0); STAGE_LOAD(rB, bx, 1, 0);
        STAGE_WRITE(rA, sAb, 1);  STAGE_WRITE(rB, sBb, 1);
        STAGE_LOAD(rA, ax, 0, 1); STAGE_LOAD(rB, bx, 0, 1);
        STAGE_WRITE(rA, sAb, 2);  STAGE_WRITE(rB, sBb, 2);
    }
    __syncthreads();

    // ---- main loop: tiles 0..NT-3 (stage targets k+1 <= NT-2, k+2 <= NT-1) ----
#pragma unroll 1
    for (int k = 0; k < NT - 2; k += 2) {
        TILE(0, k);
        TILE(2, k + 1);
    }

    // ---- epilogue: stage last 2 half-tiles, sync once, run tiles 62/63 ----
    {
        StageRegs rA, rB;
        STAGE_LOAD(rA, ax, 1, NT - 1); STAGE_WRITE(rA, sAb, 3);  // A(63,1)
        STAGE_LOAD(rB, bx, 1, NT - 1); STAGE_WRITE(rB, sBb, 3);  // B(63,1)
    }
    __syncthreads();
    TILE_NOSYNC(0);                 // tile NT-2: slots 0/1
    TILE_NOSYNC(2);                 // tile NT-1: slots 2/3

    // ---- C write: C/D layout col = lane&15, row = quad*4 + reg (m89-verified)
#pragma unroll
    for (int qm = 0; qm < 2; ++qm)
#pragma unroll
        for (int qn = 0; qn < 2; ++qn)
#pragma unroll
            for (int mt = 0; mt < 4; ++mt)
#pragma unroll
                for (int nt = 0; nt < 2; ++nt) {
                    const int col = bn * BN + qn * 128 + wqn * 32 + nt * 16 + l16;
                    const size_t row0 = (size_t)bm * BM + qm * 128 + wqm * 64
                                      + mt * 16 + quad * 4;
#pragma unroll
                    for (int r = 0; r < 4; ++r)
                        C[(row0 + r) * N_DIM + col] = acc[qm][qn][mt][nt][r];
                }
}

// Correctness fallback if M not a tile multiple (fp32 vector ALU).
__global__ __launch_bounds__(256) void gemm_naive_f32(
        const float* __restrict__ X, const float* __restrict__ W,
        float* __restrict__ C, long total) {
    long idx = (long)blockIdx.x * 256 + threadIdx.x;
    if (idx >= total) return;
    const long row = idx / N_DIM, col = idx % N_DIM;
    const float* x = X + row * K_DIM;
    const float* w = W + col * K_DIM;
    float s = 0.f;
    for (int k = 0; k < K_DIM; k += 4) {
        floatx4 a = *(const floatx4*)(x + k);
        floatx4 b = *(const floatx4*)(w + k);
        s += a[0] * b[0] + a[1] * b[1] + a[2] * b[2] + a[3] * b[3];
    }
    C[idx] = s;
}

extern "C" void kernel_launch(void* const* d_in, const int* in_sizes, int n_in,
                              void* d_out, int out_size, void* d_ws, size_t ws_size,
                              hipStream_t stream) {
    const float* x = (const float*)d_in[0];   // (4,2048,4096) fp32
    const float* w = (const float*)d_in[1];   // (4096,4096) fp32, (N,K) = B^T layout
    float* out = (float*)d_out;               // (M, 4096) fp32

    const long nx = (long)in_sizes[0];        // M*K
    const int  M  = (int)(nx / K_DIM);        // 8192

    if ((M % BM) == 0) {
        const int nwg = (M / BM) * (N_DIM / BN);   // 32*16 = 512, %8 == 0
        gemm_bf16_bt<<<dim3(nwg), 512, 0, stream>>>(x, w, out, M);
    } else {
        const long total = (long)M * N_DIM;
        gemm_naive_f32<<<(int)((total + 255) / 256), 256, 0, stream>>>(x, w, out, total);
    }
}

// Round 4
// 530.758 us; speedup vs baseline: 1.2926x; 1.2926x over previous
//
#include <hip/hip_runtime.h>
#include <cstdint>
#include <cstddef>

#define K_DIM 4096
#define N_DIM 4096
#define BM 256
#define BN 256
#define BK 64            // K-step; LDS row = 128 B = full bank period
#define NT (K_DIM / BK)  // 64 K-tiles

typedef __attribute__((ext_vector_type(8))) short short8;
typedef __attribute__((ext_vector_type(4))) float floatx4;

__device__ __forceinline__ unsigned pack_bf16x2(float lo, float hi) {
    unsigned ul = __float_as_uint(lo);
    unsigned uh = __float_as_uint(hi);
    ul = (ul + 0x7FFFu + ((ul >> 16) & 1u)) >> 16;            // RNE, low half
    uh = (uh + 0x7FFFu + ((uh >> 16) & 1u)) & 0xFFFF0000u;    // RNE, high half
    return (ul & 0xFFFFu) | uh;
}

// Fused x+w fp32->bf16 cast. 8 floats in (32 B), one uint4 out. Pure SSA pack.
__global__ __launch_bounds__(256) void cast2_f32_bf16_kernel(
        const float* __restrict__ x, const float* __restrict__ w,
        uint4* __restrict__ a16, uint4* __restrict__ b16,
        long nx, long nw) {
    const long xc = nx >> 3;
    const long total = (nx + nw) >> 3;
    long c = (long)blockIdx.x * 256 + threadIdx.x;
    const long stride = (long)gridDim.x * 256;
    for (; c < total; c += stride) {
        const float4* src;
        uint4* dst;
        if (c < xc) { src = (const float4*)x + (c << 1); dst = a16 + c; }
        else { const long d = c - xc; src = (const float4*)w + (d << 1); dst = b16 + d; }
        const float4 a = src[0];
        const float4 b = src[1];
        uint4 o;
        o.x = pack_bf16x2(a.x, a.y);
        o.y = pack_bf16x2(a.z, a.w);
        o.z = pack_bf16x2(b.x, b.y);
        o.w = pack_bf16x2(b.z, b.w);
        *dst = o;
    }
}

// ---------------------------------------------------------------------------
// bf16 GEMM, C = A * B^T. 256x256 tile / 512 threads (8 waves 2Mx4N).
// m201-style two-barrier phase skeleton on the verified r1 ring:
//   phase = { ds_reads (8 or 4, balanced) ; stage 1 half-tile (2 gload_lds) ;
//             fence ; s_barrier ; lgkmcnt(0)+sched_barrier(0) ;
//             setprio(1) ; 16 MFMA ; setprio(0) ;
//             vmcnt(6) ; fence ; s_barrier ; sched_barrier(0) }
// The phase-end vmcnt(6)+barrier covers the NEXT phase's ds_reads (reads
// execute at issue, so the covering wait must precede the read's issue).
// Tightest slot: staged 4 phases before read, 6 newer loads -> vmcnt(6). Loads
// never drained to 0 in the main loop (T4).
//
// Read balance (8,4,8,4): ph0 LDA(half0), ph1 LDB1, ph2 LDA(half1),
// ph3 pre-reads NEXT tile's bf0 (slot P0^2, staged 4 phases earlier; WAR safe:
// bf0's last MFMA use is ph2, one barrier before).
//
// LDS: ring of 4 half-tile slots per matrix (128x64 bf16 = 16 KiB each), 128 KiB
// total. Swizzle: physical 16B-block = logical_kblk ^ (row&7), staged via
// pre-swizzled per-lane GLOBAL source + linear gload_lds dest (measured
// 0-bank-conflict in r0/r1/r3).
// ---------------------------------------------------------------------------
__global__ __launch_bounds__(512, 2) void gemm_bf16_bt(
        const unsigned short* __restrict__ A,
        const unsigned short* __restrict__ B,
        float* __restrict__ C, int M) {
    __shared__ unsigned short sAb[4 * 128 * 64];   // 64 KiB
    __shared__ unsigned short sBb[4 * 128 * 64];   // 64 KiB

    const int tid  = threadIdx.x;
    const int lane = tid & 63;
    const int wave = tid >> 6;        // 0..7
    const int wqm  = wave >> 2;       // 0..1
    const int wqn  = wave & 3;        // 0..3
    const int quad = lane >> 4;       // 0..3
    const int l16  = lane & 15;

    // XCD-aware swizzle (bijective: nwg % 8 == 0 by construction)
    const int nbn = N_DIM / BN;       // 16
    int wg = blockIdx.x;
    const int cpx = gridDim.x >> 3;
    wg = (wg & 7) * cpx + (wg >> 3);
    const int bm = wg / nbn;
    const int bn = wg % nbn;

    // staging map: issue j (0..1), rows j*64 + wave*8 + (lane>>3);
    // lane writes LDS linear blk (lane&7) -> source logical kblk pre-swizzled.
    const int srow     = wave * 8 + (lane >> 3);
    const int kblk_src = (lane & 7) ^ ((lane >> 3) & 7);

    const unsigned short* ag = A + ((size_t)bm * BM + srow) * K_DIM + kblk_src * 8;
    const unsigned short* bg = B + ((size_t)bn * BN + srow) * K_DIM + kblk_src * 8;

#define STAGE(gptr, sptr, slot, half, kt)                                        \
    do {                                                                         \
        _Pragma("unroll")                                                        \
        for (int j_ = 0; j_ < 2; ++j_)                                           \
            __builtin_amdgcn_global_load_lds(                                    \
                (const __attribute__((address_space(1))) void*)(                 \
                    (gptr) + (size_t)((half) * 128 + j_ * 64) * K_DIM            \
                           + (size_t)(kt) * BK),                                 \
                (__attribute__((address_space(3))) void*)(                       \
                    (sptr) + (slot) * 8192 + (j_ * 64 + wave * 8) * BK),         \
                16, 0, 0);                                                       \
    } while (0)

    floatx4 acc[2][2][4][2];
#pragma unroll
    for (int a = 0; a < 2; ++a)
#pragma unroll
        for (int b = 0; b < 2; ++b)
#pragma unroll
            for (int c = 0; c < 4; ++c)
#pragma unroll
                for (int d = 0; d < 2; ++d)
                    acc[a][b][c][d] = (floatx4)0.0f;

    short8 af[4][2];        // A frags for current qm (reused across 2 phases)
    short8 bf0[2][2];       // B frags qn=0
    short8 bf1[2][2];       // B frags qn=1

#define LDA(slot)                                                                \
    do {                                                                         \
        _Pragma("unroll")                                                        \
        for (int mt_ = 0; mt_ < 4; ++mt_)                                        \
        _Pragma("unroll")                                                        \
        for (int ks_ = 0; ks_ < 2; ++ks_)                                        \
            af[mt_][ks_] = *(const short8*)(sAb + (slot) * 8192 +                \
                (wqm * 64 + mt_ * 16 + l16) * BK +                               \
                ((((ks_ << 2) | quad) ^ (l16 & 7)) << 3));                       \
    } while (0)

#define LDB(dst, slot)                                                           \
    do {                                                                         \
        _Pragma("unroll")                                                        \
        for (int nt_ = 0; nt_ < 2; ++nt_)                                        \
        _Pragma("unroll")                                                        \
        for (int ks_ = 0; ks_ < 2; ++ks_)                                        \
            dst[nt_][ks_] = *(const short8*)(sBb + (slot) * 8192 +               \
                (wqn * 32 + nt_ * 16 + l16) * BK +                               \
                ((((ks_ << 2) | quad) ^ (l16 & 7)) << 3));                       \
    } while (0)

#define MMA(qm, qn, bfv)                                                         \
    do {                                                                         \
        __builtin_amdgcn_s_setprio(1);                                           \
        _Pragma("unroll")                                                        \
        for (int mt_ = 0; mt_ < 4; ++mt_)                                        \
        _Pragma("unroll")                                                        \
        for (int nt_ = 0; nt_ < 2; ++nt_)                                        \
        _Pragma("unroll")                                                        \
        for (int ks_ = 0; ks_ < 2; ++ks_)                                        \
            acc[qm][qn][mt_][nt_] = __builtin_amdgcn_mfma_f32_16x16x32_bf16(     \
                af[mt_][ks_], bfv[nt_][ks_], acc[qm][qn][mt_][nt_], 0, 0, 0);    \
        __builtin_amdgcn_s_setprio(0);                                           \
    } while (0)

    // mid-phase: issue-fence, barrier, pinned lgkm drain (rule #18)
#define PH_MID                                                                   \
    do {                                                                         \
        asm volatile("" ::: "memory");                                           \
        __builtin_amdgcn_s_barrier();                                            \
        asm volatile("s_waitcnt lgkmcnt(0)" ::: "memory");                       \
        __builtin_amdgcn_sched_barrier(0);                                       \
    } while (0)

    // phase-end: counted vmcnt (covers next phase's ds_reads), barrier
#define PH_END                                                                   \
    do {                                                                         \
        asm volatile("s_waitcnt vmcnt(6)" ::: "memory");                         \
        asm volatile("" ::: "memory");                                           \
        __builtin_amdgcn_s_barrier();                                            \
        __builtin_amdgcn_sched_barrier(0);                                       \
    } while (0)

    // P0 = (k&1)*2 (compile-time via 2x loop unroll)
#define TILE(P0, k)                                                              \
    do {                                                                         \
        LDA((P0));                                     /* 8 reads  */            \
        STAGE(ag, sAb, ((P0) ^ 2) + 1, 1, (k) + 1);    /* A(k+1,1) */            \
        PH_MID; MMA(0, 0, bf0); PH_END;                                          \
        LDB(bf1, (P0) + 1);                            /* 4 reads  */            \
        STAGE(bg, sBb, ((P0) ^ 2) + 1, 1, (k) + 1);    /* B(k+1,1) */            \
        PH_MID; MMA(0, 1, bf1); PH_END;                                          \
        LDA((P0) + 1);                                 /* 8 reads  */            \
        STAGE(ag, sAb, (P0), 0, (k) + 2);              /* A(k+2,0) */            \
        PH_MID; MMA(1, 0, bf0); PH_END;                                          \
        LDB(bf0, (P0) ^ 2);                /* pre-read next tile's bf0, 4 */     \
        STAGE(bg, sBb, (P0), 0, (k) + 2);              /* B(k+2,0) */            \
        PH_MID; MMA(1, 1, bf1); PH_END;                                          \
    } while (0)

#define TILE_NOSYNC(P0)                                                          \
    do {                                                                         \
        LDA((P0));     LDB(bf0, (P0)); MMA(0, 0, bf0);                           \
        LDB(bf1, (P0) + 1);            MMA(0, 1, bf1);                           \
        LDA((P0) + 1);                 MMA(1, 0, bf0);                           \
                                       MMA(1, 1, bf1);                           \
    } while (0)

    // ---- prologue: stage A/B (0,0)->0, (0,1)->1, (1,0)->2 ----
    STAGE(ag, sAb, 0, 0, 0);
    STAGE(bg, sBb, 0, 0, 0);
    STAGE(ag, sAb, 1, 1, 0);
    STAGE(bg, sBb, 1, 1, 0);
    STAGE(ag, sAb, 2, 0, 1);
    STAGE(bg, sBb, 2, 0, 1);
    // A(0,0)+B(0,0) pairs are the 2 oldest of 12 -> vmcnt(8) retires them
    asm volatile("s_waitcnt vmcnt(8)" ::: "memory");
    asm volatile("" ::: "memory");
    __builtin_amdgcn_s_barrier();
    __builtin_amdgcn_sched_barrier(0);
    LDB(bf0, 0);        // pre-read bf0 for tile 0 (lgkm drained in ph0's PH_MID)

    // ---- main loop: tiles 0..NT-3 ----
#pragma unroll 1
    for (int k = 0; k < NT - 2; k += 2) {
        TILE(0, k);
        TILE(2, k + 1);
    }

    // ---- epilogue: last 2 half-tiles, one drain, tiles 62/63 ----
    STAGE(ag, sAb, 3, 1, NT - 1);   // A(63,1) -> slot 3
    STAGE(bg, sBb, 3, 1, NT - 1);   // B(63,1) -> slot 3
    asm volatile("s_waitcnt vmcnt(0)" ::: "memory");
    asm volatile("" ::: "memory");
    __builtin_amdgcn_s_barrier();
    __builtin_amdgcn_sched_barrier(0);
    TILE_NOSYNC(0);                 // tile NT-2: slots 0/1
    TILE_NOSYNC(2);                 // tile NT-1: slots 2/3

    // ---- C write: C/D layout col = lane&15, row = quad*4 + reg (m89-verified)
#pragma unroll
    for (int qm = 0; qm < 2; ++qm)
#pragma unroll
        for (int qn = 0; qn < 2; ++qn)
#pragma unroll
            for (int mt = 0; mt < 4; ++mt)
#pragma unroll
                for (int nt = 0; nt < 2; ++nt) {
                    const int col = bn * BN + qn * 128 + wqn * 32 + nt * 16 + l16;
                    const size_t row0 = (size_t)bm * BM + qm * 128 + wqm * 64
                                      + mt * 16 + quad * 4;
#pragma unroll
                    for (int r = 0; r < 4; ++r)
                        C[(row0 + r) * N_DIM + col] = acc[qm][qn][mt][nt][r];
                }
}

// Correctness fallback (fp32 vector ALU).
__global__ __launch_bounds__(256) void gemm_naive_f32(
        const float* __restrict__ X, const float* __restrict__ W,
        float* __restrict__ C, long total) {
    long idx = (long)blockIdx.x * 256 + threadIdx.x;
    if (idx >= total) return;
    const long row = idx / N_DIM, col = idx % N_DIM;
    const float* x = X + row * K_DIM;
    const float* w = W + col * K_DIM;
    float s = 0.f;
    for (int k = 0; k < K_DIM; k += 4) {
        floatx4 a = *(const floatx4*)(x + k);
        floatx4 b = *(const floatx4*)(w + k);
        s += a[0] * b[0] + a[1] * b[1] + a[2] * b[2] + a[3] * b[3];
    }
    C[idx] = s;
}

extern "C" void kernel_launch(void* const* d_in, const int* in_sizes, int n_in,
                              void* d_out, int out_size, void* d_ws, size_t ws_size,
                              hipStream_t stream) {
    const float* x = (const float*)d_in[0];   // (4,2048,4096) fp32
    const float* w = (const float*)d_in[1];   // (4096,4096) fp32, (N,K) = B^T layout
    float* out = (float*)d_out;               // (M, 4096) fp32

    const long nx = (long)in_sizes[0];        // M*K
    const long nw = (long)in_sizes[1];        // N*K
    const int  M  = (int)(nx / K_DIM);        // 8192

    const size_t a_bytes = (size_t)nx * 2;    // 64 MiB
    const size_t b_bytes = (size_t)nw * 2;    // 32 MiB

    if (ws_size >= a_bytes + b_bytes && (M % BM) == 0) {
        unsigned short* a16 = (unsigned short*)d_ws;
        unsigned short* b16 = (unsigned short*)((char*)d_ws + a_bytes);
        cast2_f32_bf16_kernel<<<4096, 256, 0, stream>>>(
            x, w, (uint4*)a16, (uint4*)b16, nx, nw);
        const int nwg = (M / BM) * (N_DIM / BN);   // 32*16 = 512, %8 == 0
        gemm_bf16_bt<<<dim3(nwg), 512, 0, stream>>>(a16, b16, out, M);
    } else {
        const long total = (long)M * N_DIM;
        gemm_naive_f32<<<(int)((total + 255) / 256), 256, 0, stream>>>(x, w, out, total);
    }
}

// Round 5
// 499.092 us; speedup vs baseline: 1.3746x; 1.0634x over previous
//
#include <hip/hip_runtime.h>
#include <cstdint>
#include <cstddef>

#define K_DIM 4096
#define N_DIM 4096
#define BM 256
#define BN 256
#define BK 64            // K-step; LDS row = 128 B = full bank period
#define NT (K_DIM / BK)  // 64 K-tiles

typedef __attribute__((ext_vector_type(8))) short short8;
typedef __attribute__((ext_vector_type(4))) float floatx4;

__device__ __forceinline__ unsigned pack_bf16x2(float lo, float hi) {
    unsigned ul = __float_as_uint(lo);
    unsigned uh = __float_as_uint(hi);
    ul = (ul + 0x7FFFu + ((ul >> 16) & 1u)) >> 16;            // RNE, low half
    uh = (uh + 0x7FFFu + ((uh >> 16) & 1u)) & 0xFFFF0000u;    // RNE, high half
    return (ul & 0xFFFFu) | uh;
}

// Fused x+w fp32->bf16 cast. 8 floats in (32 B), one uint4 out. Pure SSA pack.
__global__ __launch_bounds__(256) void cast2_f32_bf16_kernel(
        const float* __restrict__ x, const float* __restrict__ w,
        uint4* __restrict__ a16, uint4* __restrict__ b16,
        long nx, long nw) {
    const long xc = nx >> 3;
    const long total = (nx + nw) >> 3;
    long c = (long)blockIdx.x * 256 + threadIdx.x;
    const long stride = (long)gridDim.x * 256;
    for (; c < total; c += stride) {
        const float4* src;
        uint4* dst;
        if (c < xc) { src = (const float4*)x + (c << 1); dst = a16 + c; }
        else { const long d = c - xc; src = (const float4*)w + (d << 1); dst = b16 + d; }
        const float4 a = src[0];
        const float4 b = src[1];
        uint4 o;
        o.x = pack_bf16x2(a.x, a.y);
        o.y = pack_bf16x2(a.z, a.w);
        o.z = pack_bf16x2(b.x, b.y);
        o.w = pack_bf16x2(b.z, b.w);
        *dst = o;
    }
}

// ---------------------------------------------------------------------------
// bf16 GEMM, C = A * B^T. 256x256 tile / 512 threads (8 waves 2Mx4N).
// r1 structure with phases MERGED 4 -> 2 per K-tile (2 barriers/K-tile):
//   H0(k): stage A/B(k+1,h1); read A-h0(8) B-h0(4) B-h1(4); 32 MFMA
//          (quadrants (0,0),(0,1)); vmcnt(8); barrier.
//   H1(k): stage A/B(k+2,h0); read A-h1(8); 32 MFMA ((1,0),(1,1));
//          vmcnt(4); barrier.
// Intra-phase order is r1's proven one (stage-issue first, reads, MFMA,
// compiler-inserted fine lgkm waits — NO forced lgkm drain; r4 showed the
// drain costs ~13% MfmaUtil).
//
// Gate math (steady state): end-H0 outstanding = H1(k-1)4 + H0(k)4 = 8 ->
// vmcnt(8) is a no-op unless loads are late; end-H1 gates H0(k)'s (k+1,h1)
// stages (newer = H1(k)'s 4 -> vmcnt(4)), retirement budget ~1.2-1.5k cyc
// >= 900-cyc HBM latency. Both looser than r1's per-phase vmcnt(6).
// WAR: every restaged slot's last read is >= 1 barrier earlier (stage issued
// after the barrier; reads completed before their phase's MFMA consumed them).
//
// LDS: ring of 4 half-tile slots per matrix (128x64 bf16 = 16 KiB each),
// 128 KiB total, slot(k,h) = (2k+h)&3. Swizzle: physical 16B-block =
// logical_kblk ^ (row&7), pre-swizzled per-lane GLOBAL source + linear
// gload_lds dest (measured 0-bank-conflict in r0/r1/r3/r4).
// ---------------------------------------------------------------------------
__global__ __launch_bounds__(512, 2) void gemm_bf16_bt(
        const unsigned short* __restrict__ A,
        const unsigned short* __restrict__ B,
        float* __restrict__ C, int M) {
    __shared__ unsigned short sAb[4 * 128 * 64];   // 64 KiB
    __shared__ unsigned short sBb[4 * 128 * 64];   // 64 KiB

    const int tid  = threadIdx.x;
    const int lane = tid & 63;
    const int wave = tid >> 6;        // 0..7
    const int wqm  = wave >> 2;       // 0..1
    const int wqn  = wave & 3;        // 0..3
    const int quad = lane >> 4;       // 0..3
    const int l16  = lane & 15;

    // XCD-aware swizzle (bijective: nwg % 8 == 0 by construction)
    const int nbn = N_DIM / BN;       // 16
    int wg = blockIdx.x;
    const int cpx = gridDim.x >> 3;
    wg = (wg & 7) * cpx + (wg >> 3);
    const int bm = wg / nbn;
    const int bn = wg % nbn;

    // staging map: issue j (0..1), rows j*64 + wave*8 + (lane>>3);
    // lane writes LDS linear blk (lane&7) -> source logical kblk pre-swizzled.
    const int srow     = wave * 8 + (lane >> 3);
    const int kblk_src = (lane & 7) ^ ((lane >> 3) & 7);

    const unsigned short* ag = A + ((size_t)bm * BM + srow) * K_DIM + kblk_src * 8;
    const unsigned short* bg = B + ((size_t)bn * BN + srow) * K_DIM + kblk_src * 8;

#define STAGE(gptr, sptr, slot, half, kt)                                        \
    do {                                                                         \
        _Pragma("unroll")                                                        \
        for (int j_ = 0; j_ < 2; ++j_)                                           \
            __builtin_amdgcn_global_load_lds(                                    \
                (const __attribute__((address_space(1))) void*)(                 \
                    (gptr) + (size_t)((half) * 128 + j_ * 64) * K_DIM            \
                           + (size_t)(kt) * BK),                                 \
                (__attribute__((address_space(3))) void*)(                       \
                    (sptr) + (slot) * 8192 + (j_ * 64 + wave * 8) * BK),         \
                16, 0, 0);                                                       \
    } while (0)

    floatx4 acc[2][2][4][2];
#pragma unroll
    for (int a = 0; a < 2; ++a)
#pragma unroll
        for (int b = 0; b < 2; ++b)
#pragma unroll
            for (int c = 0; c < 4; ++c)
#pragma unroll
                for (int d = 0; d < 2; ++d)
                    acc[a][b][c][d] = (floatx4)0.0f;

    short8 af[4][2];        // A frags for current half (reused across 2 MMAs)
    short8 bf0[2][2];       // B frags qn=0 (live whole tile)
    short8 bf1[2][2];       // B frags qn=1 (live whole tile)

#define LDA(slot)                                                                \
    do {                                                                         \
        _Pragma("unroll")                                                        \
        for (int mt_ = 0; mt_ < 4; ++mt_)                                        \
        _Pragma("unroll")                                                        \
        for (int ks_ = 0; ks_ < 2; ++ks_)                                        \
            af[mt_][ks_] = *(const short8*)(sAb + (slot) * 8192 +                \
                (wqm * 64 + mt_ * 16 + l16) * BK +                               \
                ((((ks_ << 2) | quad) ^ (l16 & 7)) << 3));                       \
    } while (0)

#define LDB(dst, slot)                                                           \
    do {                                                                         \
        _Pragma("unroll")                                                        \
        for (int nt_ = 0; nt_ < 2; ++nt_)                                        \
        _Pragma("unroll")                                                        \
        for (int ks_ = 0; ks_ < 2; ++ks_)                                        \
            dst[nt_][ks_] = *(const short8*)(sBb + (slot) * 8192 +               \
                (wqn * 32 + nt_ * 16 + l16) * BK +                               \
                ((((ks_ << 2) | quad) ^ (l16 & 7)) << 3));                       \
    } while (0)

#define MMA(qm, qn, bfv)                                                         \
    do {                                                                         \
        __builtin_amdgcn_s_setprio(1);                                           \
        _Pragma("unroll")                                                        \
        for (int mt_ = 0; mt_ < 4; ++mt_)                                        \
        _Pragma("unroll")                                                        \
        for (int nt_ = 0; nt_ < 2; ++nt_)                                        \
        _Pragma("unroll")                                                        \
        for (int ks_ = 0; ks_ < 2; ++ks_)                                        \
            acc[qm][qn][mt_][nt_] = __builtin_amdgcn_mfma_f32_16x16x32_bf16(     \
                af[mt_][ks_], bfv[nt_][ks_], acc[qm][qn][mt_][nt_], 0, 0, 0);    \
        __builtin_amdgcn_s_setprio(0);                                           \
    } while (0)

#define ENDP(n)                                                                  \
    do {                                                                         \
        asm volatile("s_waitcnt vmcnt(" #n ")" ::: "memory");                    \
        asm volatile("" ::: "memory");                                           \
        __builtin_amdgcn_s_barrier();                                            \
        __builtin_amdgcn_sched_barrier(0);                                       \
    } while (0)

    // P0 = (2k)&3 (compile-time via 2x tile unroll)
#define TILE2(P0, k)                                                             \
    do {                                                                         \
        /* --- H0: quadrants (0,0),(0,1) --- */                                  \
        STAGE(ag, sAb, ((P0) ^ 2) + 1, 1, (k) + 1);    /* A(k+1,h1) */           \
        STAGE(bg, sBb, ((P0) ^ 2) + 1, 1, (k) + 1);    /* B(k+1,h1) */           \
        LDA((P0));                                     /* A-h0: 8 reads */       \
        LDB(bf0, (P0));                                /* B-h0: 4 reads */       \
        LDB(bf1, (P0) + 1);                            /* B-h1: 4 reads */       \
        MMA(0, 0, bf0);                                                          \
        MMA(0, 1, bf1);                                                          \
        ENDP(8);                                                                 \
        /* --- H1: quadrants (1,0),(1,1) --- */                                  \
        STAGE(ag, sAb, (P0), 0, (k) + 2);              /* A(k+2,h0) */           \
        STAGE(bg, sBb, (P0), 0, (k) + 2);              /* B(k+2,h0) */           \
        LDA((P0) + 1);                                 /* A-h1: 8 reads */       \
        MMA(1, 0, bf0);                                                          \
        MMA(1, 1, bf1);                                                          \
        ENDP(4);                                                                 \
    } while (0)

#define TILE2_NS(P0)                                                             \
    do {                                                                         \
        LDA((P0));     LDB(bf0, (P0)); MMA(0, 0, bf0);                           \
        LDB(bf1, (P0) + 1);            MMA(0, 1, bf1);                           \
        LDA((P0) + 1);                 MMA(1, 0, bf0);                           \
                                       MMA(1, 1, bf1);                           \
    } while (0)

    // ---- prologue: stage (0,h0)->0, (0,h1)->1, (1,h0)->2 (12 loads) ----
    STAGE(ag, sAb, 0, 0, 0);
    STAGE(bg, sBb, 0, 0, 0);
    STAGE(ag, sAb, 1, 1, 0);
    STAGE(bg, sBb, 1, 1, 0);
    STAGE(ag, sAb, 2, 0, 1);
    STAGE(bg, sBb, 2, 0, 1);
    // tile 0's 8 loads are the oldest of 12 -> vmcnt(4) retires them
    asm volatile("s_waitcnt vmcnt(4)" ::: "memory");
    asm volatile("" ::: "memory");
    __builtin_amdgcn_s_barrier();
    __builtin_amdgcn_sched_barrier(0);

    // ---- main loop: tiles 0..NT-3 (62 tiles, stages through (NT-1,h0)) ----
#pragma unroll 1
    for (int k = 0; k < NT - 2; k += 2) {
        TILE2(0, k);
        TILE2(2, k + 1);
    }

    // ---- epilogue: stage (NT-1,h1)->slot 3, drain once, tiles 62/63 ----
    STAGE(ag, sAb, 3, 1, NT - 1);
    STAGE(bg, sBb, 3, 1, NT - 1);
    asm volatile("s_waitcnt vmcnt(0)" ::: "memory");
    asm volatile("" ::: "memory");
    __builtin_amdgcn_s_barrier();
    __builtin_amdgcn_sched_barrier(0);
    TILE2_NS(0);                    // tile NT-2: slots 0/1
    TILE2_NS(2);                    // tile NT-1: slots 2/3

    // ---- C write: C/D layout col = lane&15, row = quad*4 + reg (m89-verified)
#pragma unroll
    for (int qm = 0; qm < 2; ++qm)
#pragma unroll
        for (int qn = 0; qn < 2; ++qn)
#pragma unroll
            for (int mt = 0; mt < 4; ++mt)
#pragma unroll
                for (int nt = 0; nt < 2; ++nt) {
                    const int col = bn * BN + qn * 128 + wqn * 32 + nt * 16 + l16;
                    const size_t row0 = (size_t)bm * BM + qm * 128 + wqm * 64
                                      + mt * 16 + quad * 4;
#pragma unroll
                    for (int r = 0; r < 4; ++r)
                        C[(row0 + r) * N_DIM + col] = acc[qm][qn][mt][nt][r];
                }
}

// Correctness fallback (fp32 vector ALU).
__global__ __launch_bounds__(256) void gemm_naive_f32(
        const float* __restrict__ X, const float* __restrict__ W,
        float* __restrict__ C, long total) {
    long idx = (long)blockIdx.x * 256 + threadIdx.x;
    if (idx >= total) return;
    const long row = idx / N_DIM, col = idx % N_DIM;
    const float* x = X + row * K_DIM;
    const float* w = W + col * K_DIM;
    float s = 0.f;
    for (int k = 0; k < K_DIM; k += 4) {
        floatx4 a = *(const floatx4*)(x + k);
        floatx4 b = *(const floatx4*)(w + k);
        s += a[0] * b[0] + a[1] * b[1] + a[2] * b[2] + a[3] * b[3];
    }
    C[idx] = s;
}

extern "C" void kernel_launch(void* const* d_in, const int* in_sizes, int n_in,
                              void* d_out, int out_size, void* d_ws, size_t ws_size,
                              hipStream_t stream) {
    const float* x = (const float*)d_in[0];   // (4,2048,4096) fp32
    const float* w = (const float*)d_in[1];   // (4096,4096) fp32, (N,K) = B^T layout
    float* out = (float*)d_out;               // (M, 4096) fp32

    const long nx = (long)in_sizes[0];        // M*K
    const long nw = (long)in_sizes[1];        // N*K
    const int  M  = (int)(nx / K_DIM);        // 8192

    const size_t a_bytes = (size_t)nx * 2;    // 64 MiB
    const size_t b_bytes = (size_t)nw * 2;    // 32 MiB

    if (ws_size >= a_bytes + b_bytes && (M % BM) == 0) {
        unsigned short* a16 = (unsigned short*)d_ws;
        unsigned short* b16 = (unsigned short*)((char*)d_ws + a_bytes);
        cast2_f32_bf16_kernel<<<4096, 256, 0, stream>>>(
            x, w, (uint4*)a16, (uint4*)b16, nx, nw);
        const int nwg = (M / BM) * (N_DIM / BN);   // 32*16 = 512, %8 == 0
        gemm_bf16_bt<<<dim3(nwg), 512, 0, stream>>>(a16, b16, out, M);
    } else {
        const long total = (long)M * N_DIM;
        gemm_naive_f32<<<(int)((total + 255) / 256), 256, 0, stream>>>(x, w, out, total);
    }
}